// Round 2
// 485.416 us; speedup vs baseline: 1.0132x; 1.0132x over previous
//
#include <hip/hip_runtime.h>

typedef _Float16 f16;
typedef __attribute__((ext_vector_type(8))) _Float16 f16x8;
typedef __attribute__((ext_vector_type(4))) _Float16 f16x4;
typedef __attribute__((ext_vector_type(4))) float f32x4;

constexpr int HQ = 32, HKV = 8, D = 128, NB = 8, S = 1024;
constexpr float SCALE_LOG2E = 0.08838834764831845f * 1.4426950408889634f;

// ---- kpack: k fp32 [t][h][d] -> fragment-major f16 ----
// OUTPUT layout unchanged: chunk c = [b][hk][tile(16)][mb(4)][kb(4)][lane(64)] of 8 f16:
//   element j: K[s = tile*64+mb*16+lq][d = kb*32+quad*8+j]   (lane = quad*16+lq)
// Thread mapping: block = (b,hk,tile,mb); thread t: s_local=t>>4, dg=t&15.
// Reads: 16 consecutive threads cover 512B contiguous for one s -> fully coalesced.
__global__ __launch_bounds__(256) void kpack_kernel(const float* __restrict__ k,
                                                    f16* __restrict__ kf) {
    int blk = blockIdx.x;                     // 4096 = b(8) hk(8) tile(16) mb(4)
    int mb = blk & 3, tile = (blk >> 2) & 15, hk = (blk >> 6) & 7, b = blk >> 9;
    int t = threadIdx.x;
    int s_local = t >> 4;                     // 0..15
    int dg = t & 15;                          // d-group: d = dg*8
    int s = tile * 64 + mb * 16 + s_local;
    const float* src = k + ((size_t)(b * S + s) * HKV + hk) * D + dg * 8;
    float4 x = *(const float4*)src;
    float4 y = *(const float4*)(src + 4);
    f16x8 o = { (f16)x.x,(f16)x.y,(f16)x.z,(f16)x.w,
                (f16)y.x,(f16)y.y,(f16)y.z,(f16)y.w };
    int kb = dg >> 2, quad = dg & 3;
    size_t c = ((((size_t)(b * 8 + hk) * 16 + tile) * 4 + mb) * 4 + kb) * 64
             + quad * 16 + s_local;
    *(f16x8*)(kf + c * 8) = o;
}

// ---- vpack: v fp32 [t][h][d] -> V^T fragment-major f16 (ks pairs) ----
// chunk c -> [b][hk][tile(16)][mi(8)][ks2(2)][lane(64)] of 8 f16:
//   element (o,j): V[s = tile*64+ks2*32+o*16+quad*4+j][d = mi*16+lq]
__global__ __launch_bounds__(256) void vpack_kernel(const float* __restrict__ v,
                                                    f16* __restrict__ vf) {
    int c = blockIdx.x * 256 + threadIdx.x;   // 2^20 chunks
    int lane = c & 63;
    int ks2 = (c >> 6) & 1, mi = (c >> 7) & 7, tile = (c >> 10) & 15;
    int hk = (c >> 14) & 7, b = (c >> 17);
    int quad = lane >> 4, lq = lane & 15;
    int d = mi * 16 + lq;
    f16 buf[8];
#pragma unroll
    for (int o = 0; o < 2; o++)
#pragma unroll
        for (int j = 0; j < 4; j++) {
            int s = tile * 64 + ks2 * 32 + o * 16 + quad * 4 + j;
            buf[o * 4 + j] = (f16)v[((size_t)(b * S + s) * HKV + hk) * D + d];
        }
    *(f16x8*)(vf + (size_t)c * 8) = *(const f16x8*)buf;
}

// ---- attention: barrier-free causal GQA flash; all operands global ----
// XCD-aligned swizzle: all 32 blocks of one (b,hk) group land on one XCD
// (bid & 7 == XCD on MI355X round-robin dispatch) so the 512 KB kf/vf working
// set stays L2-resident per XCD (~2-3 groups live at a time -> ~1.5 MB).
__global__ __launch_bounds__(256, 3) void attn_kernel(
    const float* __restrict__ q, const f16* __restrict__ kf,
    const f16* __restrict__ vf, float* __restrict__ out) {

    int id = blockIdx.x;
    int xcd = id & 7;
    int slot = id >> 3;                // 0..255 within XCD
    int gl = slot >> 5;                // 0..7: group-local index on this XCD
    int inner = slot & 31;             // 0..31: 4 q-heads x 8 q-tiles
    int g = gl * 8 + xcd;              // (b,hk) group 0..63
    int b = g >> 3, hk = g & 7;
    int hq = (hk << 2) | (inner & 3);
    int qt = 7 - (inner >> 2);         // heavy q-tiles dispatch first

    int t = threadIdx.x;
    int w = t >> 6, lane = t & 63, quad = lane >> 4, lq = lane & 15;
    int qwb = qt * 128 + w * 32;       // wave's first query

    // Q fragments, pre-scaled by SCALE_LOG2E (kills 32 VALU muls per tile)
    f16x8 qf[2][4];
#pragma unroll
    for (int nq = 0; nq < 2; nq++) {
        int qg = qwb + nq * 16 + lq;
        const float* qp = q + ((size_t)(b * S + qg) * HQ + hq) * D + quad * 8;
#pragma unroll
        for (int kb = 0; kb < 4; kb++) {
            float4 x = *(const float4*)(qp + kb * 32);
            float4 y = *(const float4*)(qp + kb * 32 + 4);
            qf[nq][kb] = (f16x8){
                (f16)(x.x * SCALE_LOG2E), (f16)(x.y * SCALE_LOG2E),
                (f16)(x.z * SCALE_LOG2E), (f16)(x.w * SCALE_LOG2E),
                (f16)(y.x * SCALE_LOG2E), (f16)(y.y * SCALE_LOG2E),
                (f16)(y.z * SCALE_LOG2E), (f16)(y.w * SCALE_LOG2E) };
        }
    }

    f32x4 zero4 = { 0.f, 0.f, 0.f, 0.f };
    f32x4 oacc[8][2];
#pragma unroll
    for (int mi = 0; mi < 8; mi++) { oacc[mi][0] = zero4; oacc[mi][1] = zero4; }
    float m_i[2] = { -1e30f, -1e30f };
    float l_i[2] = { 0.f, 0.f };

    const f16* kfb = kf + (size_t)(b * 8 + hk) * (S * D);
    const f16* vfb = vf + (size_t)(b * 8 + hk) * (S * D);

    int nt = qwb / 64 + 1;             // tiles needed (causal)

    for (int kt = 0; kt < nt; kt++) {
        // S^T = K_tile . Q^T   (scores arrive pre-scaled in log2 domain)
        f32x4 sacc[4][2];
#pragma unroll
        for (int mb = 0; mb < 4; mb++) { sacc[mb][0] = zero4; sacc[mb][1] = zero4; }
        __builtin_amdgcn_s_setprio(1);
#pragma unroll
        for (int mb = 0; mb < 4; mb++) {
            const f16* ka = kfb + (size_t)(((kt * 4 + mb) * 4) * 64 + lane) * 8;
#pragma unroll
            for (int kb = 0; kb < 4; kb++) {
                f16x8 af = *(const f16x8*)(ka + kb * 512);
                sacc[mb][0] = __builtin_amdgcn_mfma_f32_16x16x32_f16(af, qf[0][kb], sacc[mb][0], 0, 0, 0);
                sacc[mb][1] = __builtin_amdgcn_mfma_f32_16x16x32_f16(af, qf[1][kb], sacc[mb][1], 0, 0, 0);
            }
        }
        __builtin_amdgcn_s_setprio(0);

        // online softmax with defer-max (T13, THR=8 in log2 domain)
        bool diag = (kt == nt - 1);
        f16x4 pf[4][2];
#pragma unroll
        for (int nq = 0; nq < 2; nq++) {
            float mt = -1e30f;
            if (diag) {
                int qg = qwb + nq * 16 + lq;
#pragma unroll
                for (int mb = 0; mb < 4; mb++)
#pragma unroll
                    for (int r4 = 0; r4 < 4; r4++) {
                        float vs = sacc[mb][nq][r4];
                        int key = kt * 64 + mb * 16 + quad * 4 + r4;
                        vs = (key <= qg) ? vs : -1e30f;
                        sacc[mb][nq][r4] = vs;
                        mt = fmaxf(mt, vs);
                    }
            } else {
#pragma unroll
                for (int mb = 0; mb < 4; mb++)
#pragma unroll
                    for (int r4 = 0; r4 < 4; r4++)
                        mt = fmaxf(mt, sacc[mb][nq][r4]);
            }
            mt = fmaxf(mt, __shfl_xor(mt, 16, 64));
            mt = fmaxf(mt, __shfl_xor(mt, 32, 64));
            float mnew = m_i[nq];
            if (!__all(mt <= mnew + 8.0f)) {   // wave-uniform: rescale rarely
                mnew = fmaxf(mnew, mt);
                float a = exp2f(m_i[nq] - mnew);
                m_i[nq] = mnew;
                l_i[nq] *= a;
#pragma unroll
                for (int mi = 0; mi < 8; mi++) oacc[mi][nq] = oacc[mi][nq] * a;
            }
            float ls = 0.f;
#pragma unroll
            for (int mb = 0; mb < 4; mb++) {
#pragma unroll
                for (int r4 = 0; r4 < 4; r4++) {
                    float e = exp2f(sacc[mb][nq][r4] - mnew);
                    sacc[mb][nq][r4] = e;
                    ls += e;
                }
                auto lo = __builtin_amdgcn_cvt_pkrtz(sacc[mb][nq][0], sacc[mb][nq][1]);
                auto hi = __builtin_amdgcn_cvt_pkrtz(sacc[mb][nq][2], sacc[mb][nq][3]);
                pf[mb][nq] = (f16x4){ (f16)lo[0], (f16)lo[1], (f16)hi[0], (f16)hi[1] };
            }
            ls += __shfl_xor(ls, 16, 64);
            ls += __shfl_xor(ls, 32, 64);
            l_i[nq] += ls;
        }

        // O^T += V^T . P^T  (A-frags b128 from global, B straight from regs)
        __builtin_amdgcn_s_setprio(1);
#pragma unroll
        for (int mi = 0; mi < 8; mi++) {
            const f16* va = vfb + (size_t)(((kt * 8 + mi) * 2) * 64 + lane) * 8;
#pragma unroll
            for (int ks2 = 0; ks2 < 2; ks2++) {
                f16x8 vv = *(const f16x8*)(va + ks2 * 512);
                f16x4 v0 = { vv[0], vv[1], vv[2], vv[3] };
                f16x4 v1 = { vv[4], vv[5], vv[6], vv[7] };
                oacc[mi][0] = __builtin_amdgcn_mfma_f32_16x16x16f16(v0, pf[ks2 * 2 + 0][0], oacc[mi][0], 0, 0, 0);
                oacc[mi][0] = __builtin_amdgcn_mfma_f32_16x16x16f16(v1, pf[ks2 * 2 + 1][0], oacc[mi][0], 0, 0, 0);
                oacc[mi][1] = __builtin_amdgcn_mfma_f32_16x16x16f16(v0, pf[ks2 * 2 + 0][1], oacc[mi][1], 0, 0, 0);
                oacc[mi][1] = __builtin_amdgcn_mfma_f32_16x16x16f16(v1, pf[ks2 * 2 + 1][1], oacc[mi][1], 0, 0, 0);
            }
        }
        __builtin_amdgcn_s_setprio(0);
    }

    // epilogue
#pragma unroll
    for (int nq = 0; nq < 2; nq++) {
        float linv = 1.0f / l_i[nq];
        int qg = qwb + nq * 16 + lq;
        float* op = out + ((size_t)(b * S + qg) * HQ + hq) * D + quad * 4;
#pragma unroll
        for (int mi = 0; mi < 8; mi++) {
            float4 vv = { oacc[mi][nq][0] * linv, oacc[mi][nq][1] * linv,
                          oacc[mi][nq][2] * linv, oacc[mi][nq][3] * linv };
            *(float4*)(op + mi * 16) = vv;
        }
    }
}

extern "C" void kernel_launch(void* const* d_in, const int* in_sizes, int n_in,
                              void* d_out, int out_size, void* d_ws, size_t ws_size,
                              hipStream_t stream) {
    (void)in_sizes; (void)n_in; (void)out_size; (void)ws_size;
    const float* q = (const float*)d_in[0];
    const float* k = (const float*)d_in[1];
    const float* v = (const float*)d_in[2];
    // paged-cache scatter/gather round-trip is identity for the output -> skip
    float* out = (float*)d_out;

    f16* kf = (f16*)d_ws;                                  // 16.8 MB
    f16* vf = kf + (size_t)NB * HKV * S * D;               // 16.8 MB

    kpack_kernel<<<4096, 256, 0, stream>>>(k, kf);
    vpack_kernel<<<4096, 256, 0, stream>>>(v, vf);
    attn_kernel<<<NB * HQ * 8, 256, 0, stream>>>(q, kf, vf, out);
}

// Round 3
// 482.394 us; speedup vs baseline: 1.0196x; 1.0063x over previous
//
#include <hip/hip_runtime.h>

typedef _Float16 f16;
typedef __attribute__((ext_vector_type(8))) _Float16 f16x8;
typedef __attribute__((ext_vector_type(4))) _Float16 f16x4;
typedef __attribute__((ext_vector_type(4))) float f32x4;

constexpr int HQ = 32, HKV = 8, D = 128, NB = 8, S = 1024;
constexpr float SCALE_LOG2E = 0.08838834764831845f * 1.4426950408889634f;

// ---- kpack: k fp32 [t][h][d] -> fragment-major f16 ----
// chunk c = [b][hk][tile(16)][mb(4)][kb(4)][lane(64)] of 8 f16:
//   element j: K[s = tile*64+mb*16+lq][d = kb*32+quad*8+j]   (lane = quad*16+lq)
__global__ __launch_bounds__(256) void kpack_kernel(const float* __restrict__ k,
                                                    f16* __restrict__ kf) {
    int blk = blockIdx.x;                     // 4096 = b(8) hk(8) tile(16) mb(4)
    int mb = blk & 3, tile = (blk >> 2) & 15, hk = (blk >> 6) & 7, b = blk >> 9;
    int t = threadIdx.x;
    int s_local = t >> 4;                     // 0..15
    int dg = t & 15;                          // d-group: d = dg*8
    int s = tile * 64 + mb * 16 + s_local;
    const float* src = k + ((size_t)(b * S + s) * HKV + hk) * D + dg * 8;
    float4 x = *(const float4*)src;
    float4 y = *(const float4*)(src + 4);
    f16x8 o = { (f16)x.x,(f16)x.y,(f16)x.z,(f16)x.w,
                (f16)y.x,(f16)y.y,(f16)y.z,(f16)y.w };
    int kb = dg >> 2, quad = dg & 3;
    size_t c = ((((size_t)(b * 8 + hk) * 16 + tile) * 4 + mb) * 4 + kb) * 64
             + quad * 16 + s_local;
    *(f16x8*)(kf + c * 8) = o;
}

// ---- vpack: v fp32 [t][h][d] -> V^T fragment-major f16 (ks pairs) ----
// chunk c -> [b][hk][tile(16)][mi(8)][ks2(2)][lane(64)] of 8 f16:
//   element (o,j): V[s = tile*64+ks2*32+o*16+quad*4+j][d = mi*16+lq]
__global__ __launch_bounds__(256) void vpack_kernel(const float* __restrict__ v,
                                                    f16* __restrict__ vf) {
    int c = blockIdx.x * 256 + threadIdx.x;   // 2^20 chunks
    int lane = c & 63;
    int ks2 = (c >> 6) & 1, mi = (c >> 7) & 7, tile = (c >> 10) & 15;
    int hk = (c >> 14) & 7, b = (c >> 17);
    int quad = lane >> 4, lq = lane & 15;
    int d = mi * 16 + lq;
    f16 buf[8];
#pragma unroll
    for (int o = 0; o < 2; o++)
#pragma unroll
        for (int j = 0; j < 4; j++) {
            int s = tile * 64 + ks2 * 32 + o * 16 + quad * 4 + j;
            buf[o * 4 + j] = (f16)v[((size_t)(b * S + s) * HKV + hk) * D + d];
        }
    *(f16x8*)(vf + (size_t)c * 8) = *(const f16x8*)buf;
}

// ---- attention: barrier-free causal GQA flash; all operands global ----
// XCD-aligned swizzle: all 32 blocks of one (b,hk) group land on one XCD
// (id & 7 == XCD round-robin) -> 512 KB KV working set stays L2-resident.
// qt ROTATED BY gl: CU c's 8 blocks (one per gl group) span all 8 qt values,
// equalizing per-CU work (round-2 regression: fixed qt per CU -> 2x imbalance).
__global__ __launch_bounds__(256, 3) void attn_kernel(
    const float* __restrict__ q, const f16* __restrict__ kf,
    const f16* __restrict__ vf, float* __restrict__ out) {

    int id = blockIdx.x;
    int xcd = id & 7;
    int slot = id >> 3;                // 0..255 within XCD
    int gl = slot >> 5;                // 0..7: group-local index on this XCD
    int inner = slot & 31;             // 0..31: 4 q-heads x 8 q-tiles
    int g = gl * 8 + xcd;              // (b,hk) group 0..63
    int b = g >> 3, hk = g & 7;
    int hq = (hk << 2) | (inner & 3);
    int qt = 7 - (((inner >> 2) + gl) & 7);   // balanced rotation, still bijective

    int t = threadIdx.x;
    int w = t >> 6, lane = t & 63, quad = lane >> 4, lq = lane & 15;
    int qwb = qt * 128 + w * 32;       // wave's first query

    // Q fragments, pre-scaled by SCALE_LOG2E
    f16x8 qf[2][4];
#pragma unroll
    for (int nq = 0; nq < 2; nq++) {
        int qg = qwb + nq * 16 + lq;
        const float* qp = q + ((size_t)(b * S + qg) * HQ + hq) * D + quad * 8;
#pragma unroll
        for (int kb = 0; kb < 4; kb++) {
            float4 x = *(const float4*)(qp + kb * 32);
            float4 y = *(const float4*)(qp + kb * 32 + 4);
            qf[nq][kb] = (f16x8){
                (f16)(x.x * SCALE_LOG2E), (f16)(x.y * SCALE_LOG2E),
                (f16)(x.z * SCALE_LOG2E), (f16)(x.w * SCALE_LOG2E),
                (f16)(y.x * SCALE_LOG2E), (f16)(y.y * SCALE_LOG2E),
                (f16)(y.z * SCALE_LOG2E), (f16)(y.w * SCALE_LOG2E) };
        }
    }

    f32x4 zero4 = { 0.f, 0.f, 0.f, 0.f };
    f32x4 oacc[8][2];
#pragma unroll
    for (int mi = 0; mi < 8; mi++) { oacc[mi][0] = zero4; oacc[mi][1] = zero4; }
    float m_i[2] = { -1e30f, -1e30f };
    float l_i[2] = { 0.f, 0.f };

    const f16* kfb = kf + (size_t)(b * 8 + hk) * (S * D);
    const f16* vfb = vf + (size_t)(b * 8 + hk) * (S * D);

    int nt = qwb / 64 + 1;             // tiles needed (causal)

    for (int kt = 0; kt < nt; kt++) {
        // S^T = K_tile . Q^T   (scores arrive pre-scaled in log2 domain)
        f32x4 sacc[4][2];
#pragma unroll
        for (int mb = 0; mb < 4; mb++) { sacc[mb][0] = zero4; sacc[mb][1] = zero4; }
        __builtin_amdgcn_s_setprio(1);
#pragma unroll
        for (int mb = 0; mb < 4; mb++) {
            const f16* ka = kfb + (size_t)(((kt * 4 + mb) * 4) * 64 + lane) * 8;
#pragma unroll
            for (int kb = 0; kb < 4; kb++) {
                f16x8 af = *(const f16x8*)(ka + kb * 512);
                sacc[mb][0] = __builtin_amdgcn_mfma_f32_16x16x32_f16(af, qf[0][kb], sacc[mb][0], 0, 0, 0);
                sacc[mb][1] = __builtin_amdgcn_mfma_f32_16x16x32_f16(af, qf[1][kb], sacc[mb][1], 0, 0, 0);
            }
        }
        __builtin_amdgcn_s_setprio(0);

        // online softmax with defer-max (THR=8 in log2 domain)
        bool diag = (kt == nt - 1);
        f16x4 pf[4][2];
#pragma unroll
        for (int nq = 0; nq < 2; nq++) {
            float mt = -1e30f;
            if (diag) {
                int qg = qwb + nq * 16 + lq;
#pragma unroll
                for (int mb = 0; mb < 4; mb++)
#pragma unroll
                    for (int r4 = 0; r4 < 4; r4++) {
                        float vs = sacc[mb][nq][r4];
                        int key = kt * 64 + mb * 16 + quad * 4 + r4;
                        vs = (key <= qg) ? vs : -1e30f;
                        sacc[mb][nq][r4] = vs;
                        mt = fmaxf(mt, vs);
                    }
            } else {
#pragma unroll
                for (int mb = 0; mb < 4; mb++)
#pragma unroll
                    for (int r4 = 0; r4 < 4; r4++)
                        mt = fmaxf(mt, sacc[mb][nq][r4]);
            }
            mt = fmaxf(mt, __shfl_xor(mt, 16, 64));
            mt = fmaxf(mt, __shfl_xor(mt, 32, 64));
            float mnew = m_i[nq];
            if (!__all(mt <= mnew + 8.0f)) {   // wave-uniform: rescale rarely
                mnew = fmaxf(mnew, mt);
                float a = exp2f(m_i[nq] - mnew);
                m_i[nq] = mnew;
                l_i[nq] *= a;
#pragma unroll
                for (int mi = 0; mi < 8; mi++) oacc[mi][nq] = oacc[mi][nq] * a;
            }
            float ls = 0.f;
#pragma unroll
            for (int mb = 0; mb < 4; mb++) {
#pragma unroll
                for (int r4 = 0; r4 < 4; r4++) {
                    float e = exp2f(sacc[mb][nq][r4] - mnew);
                    sacc[mb][nq][r4] = e;
                    ls += e;
                }
                auto lo = __builtin_amdgcn_cvt_pkrtz(sacc[mb][nq][0], sacc[mb][nq][1]);
                auto hi = __builtin_amdgcn_cvt_pkrtz(sacc[mb][nq][2], sacc[mb][nq][3]);
                pf[mb][nq] = (f16x4){ (f16)lo[0], (f16)lo[1], (f16)hi[0], (f16)hi[1] };
            }
            ls += __shfl_xor(ls, 16, 64);
            ls += __shfl_xor(ls, 32, 64);
            l_i[nq] += ls;
        }

        // O^T += V^T . P^T  (A-frags b128 from global, B straight from regs)
        __builtin_amdgcn_s_setprio(1);
#pragma unroll
        for (int mi = 0; mi < 8; mi++) {
            const f16* va = vfb + (size_t)(((kt * 8 + mi) * 2) * 64 + lane) * 8;
#pragma unroll
            for (int ks2 = 0; ks2 < 2; ks2++) {
                f16x8 vv = *(const f16x8*)(va + ks2 * 512);
                f16x4 v0 = { vv[0], vv[1], vv[2], vv[3] };
                f16x4 v1 = { vv[4], vv[5], vv[6], vv[7] };
                oacc[mi][0] = __builtin_amdgcn_mfma_f32_16x16x16f16(v0, pf[ks2 * 2 + 0][0], oacc[mi][0], 0, 0, 0);
                oacc[mi][0] = __builtin_amdgcn_mfma_f32_16x16x16f16(v1, pf[ks2 * 2 + 1][0], oacc[mi][0], 0, 0, 0);
                oacc[mi][1] = __builtin_amdgcn_mfma_f32_16x16x16f16(v0, pf[ks2 * 2 + 0][1], oacc[mi][1], 0, 0, 0);
                oacc[mi][1] = __builtin_amdgcn_mfma_f32_16x16x16f16(v1, pf[ks2 * 2 + 1][1], oacc[mi][1], 0, 0, 0);
            }
        }
        __builtin_amdgcn_s_setprio(0);
    }

    // epilogue
#pragma unroll
    for (int nq = 0; nq < 2; nq++) {
        float linv = 1.0f / l_i[nq];
        int qg = qwb + nq * 16 + lq;
        float* op = out + ((size_t)(b * S + qg) * HQ + hq) * D + quad * 4;
#pragma unroll
        for (int mi = 0; mi < 8; mi++) {
            float4 vv = { oacc[mi][nq][0] * linv, oacc[mi][nq][1] * linv,
                          oacc[mi][nq][2] * linv, oacc[mi][nq][3] * linv };
            *(float4*)(op + mi * 16) = vv;
        }
    }
}

extern "C" void kernel_launch(void* const* d_in, const int* in_sizes, int n_in,
                              void* d_out, int out_size, void* d_ws, size_t ws_size,
                              hipStream_t stream) {
    (void)in_sizes; (void)n_in; (void)out_size; (void)ws_size;
    const float* q = (const float*)d_in[0];
    const float* k = (const float*)d_in[1];
    const float* v = (const float*)d_in[2];
    // paged-cache scatter/gather round-trip is identity for the output -> skip
    float* out = (float*)d_out;

    f16* kf = (f16*)d_ws;                                  // 16.8 MB
    f16* vf = kf + (size_t)NB * HKV * S * D;               // 16.8 MB

    kpack_kernel<<<4096, 256, 0, stream>>>(k, kf);
    vpack_kernel<<<4096, 256, 0, stream>>>(v, vf);
    attn_kernel<<<NB * HQ * 8, 256, 0, stream>>>(q, kf, vf, out);
}

// Round 4
// 460.877 us; speedup vs baseline: 1.0672x; 1.0467x over previous
//
#include <hip/hip_runtime.h>

typedef _Float16 f16;
typedef __attribute__((ext_vector_type(8))) _Float16 f16x8;
typedef __attribute__((ext_vector_type(4))) _Float16 f16x4;
typedef __attribute__((ext_vector_type(4))) float f32x4;

constexpr int HQ = 32, HKV = 8, D = 128, NB = 8, S = 1024;
constexpr float SCALE_LOG2E = 0.08838834764831845f * 1.4426950408889634f;

// ---- pack: K and V fp32 [t][h][d] -> fragment-major f16, via LDS transpose ----
// Block = (b, hk, tile of 64 tokens). Reads fully coalesced (float4, consecutive
// threads -> consecutive addresses), writes fully coalesced (consecutive threads
// -> consecutive 16B chunks). Replaces old kpack (scattered 16B writes) and
// vpack (8x 4B gathers at 4KB stride per thread -- the ~200us hotspot).
// K chunk layout (unchanged): c = [b][hk][tile(16)][mb(4)][kb(4)][lane(64)], elem j:
//   K[s = tile*64+mb*16+lq][d = kb*32+quad*8+j],  lane = quad*16+lq
// V chunk layout (unchanged): c = [b][hk][tile(16)][mi(8)][ks2(2)][lane(64)], elem (o,j):
//   V[s = tile*64+ks2*32+o*16+quad*4+j][d = mi*16+lq]
__global__ __launch_bounds__(256) void pack_kernel(const float* __restrict__ k,
                                                   const float* __restrict__ v,
                                                   f16* __restrict__ kf,
                                                   f16* __restrict__ vf) {
    __shared__ __attribute__((aligned(16))) f16 tile[64][136];  // 272B row: 16B-aligned, bank-spread
    int blk = blockIdx.x;              // 1024 = b(8) hk(8) tile(16)
    int tl = blk & 15, hk = (blk >> 4) & 7, b = blk >> 7;
    int t = threadIdx.x;
    size_t cbase = ((size_t)(b * 8 + hk) * 16 + tl) * 1024;   // chunk base for this tile

    // ---- K: coalesced read -> LDS ----
    const float* kin = k + ((size_t)(b * S + tl * 64) * HKV + hk) * D;
#pragma unroll
    for (int i = 0; i < 8; i++) {
        int flat = t + 256 * i;          // float4 index within 64x128 tile
        int row = flat >> 5, c4 = flat & 31;
        float4 x = *(const float4*)(kin + (size_t)row * (HKV * D) + c4 * 4);
        *(f16x4*)&tile[row][c4 * 4] = (f16x4){ (f16)x.x,(f16)x.y,(f16)x.z,(f16)x.w };
    }
    __syncthreads();
    // ---- K: LDS -> coalesced fragment writes ----
#pragma unroll
    for (int i = 0; i < 4; i++) {
        int c_loc = t + 256 * i;
        int mb = c_loc >> 8, kb = (c_loc >> 6) & 3, lane = c_loc & 63;
        int quad = lane >> 4, lq = lane & 15;
        f16x8 o = *(const f16x8*)&tile[mb * 16 + lq][kb * 32 + quad * 8];
        *(f16x8*)(kf + (cbase + c_loc) * 8) = o;
    }
    __syncthreads();

    // ---- V: coalesced read -> LDS ----
    const float* vin = v + ((size_t)(b * S + tl * 64) * HKV + hk) * D;
#pragma unroll
    for (int i = 0; i < 8; i++) {
        int flat = t + 256 * i;
        int row = flat >> 5, c4 = flat & 31;
        float4 x = *(const float4*)(vin + (size_t)row * (HKV * D) + c4 * 4);
        *(f16x4*)&tile[row][c4 * 4] = (f16x4){ (f16)x.x,(f16)x.y,(f16)x.z,(f16)x.w };
    }
    __syncthreads();
    // ---- V: LDS transpose -> coalesced fragment writes ----
#pragma unroll
    for (int i = 0; i < 4; i++) {
        int c_loc = t + 256 * i;
        int mi = c_loc >> 7, ks2 = (c_loc >> 6) & 1, lane = c_loc & 63;
        int quad = lane >> 4, lq = lane & 15;
        int d = mi * 16 + lq;
        f16 buf[8];
#pragma unroll
        for (int o = 0; o < 2; o++)
#pragma unroll
            for (int j = 0; j < 4; j++)
                buf[o * 4 + j] = tile[ks2 * 32 + o * 16 + quad * 4 + j][d];
        *(f16x8*)(vf + (cbase + c_loc) * 8) = *(const f16x8*)buf;
    }
}

// ---- attention: unchanged from round 3 (byte-identical operand layouts) ----
__global__ __launch_bounds__(256, 3) void attn_kernel(
    const float* __restrict__ q, const f16* __restrict__ kf,
    const f16* __restrict__ vf, float* __restrict__ out) {

    int id = blockIdx.x;
    int xcd = id & 7;
    int slot = id >> 3;                // 0..255 within XCD
    int gl = slot >> 5;                // 0..7: group-local index on this XCD
    int inner = slot & 31;             // 0..31: 4 q-heads x 8 q-tiles
    int g = gl * 8 + xcd;              // (b,hk) group 0..63
    int b = g >> 3, hk = g & 7;
    int hq = (hk << 2) | (inner & 3);
    int qt = 7 - (((inner >> 2) + gl) & 7);

    int t = threadIdx.x;
    int w = t >> 6, lane = t & 63, quad = lane >> 4, lq = lane & 15;
    int qwb = qt * 128 + w * 32;       // wave's first query

    // Q fragments, pre-scaled by SCALE_LOG2E
    f16x8 qf[2][4];
#pragma unroll
    for (int nq = 0; nq < 2; nq++) {
        int qg = qwb + nq * 16 + lq;
        const float* qp = q + ((size_t)(b * S + qg) * HQ + hq) * D + quad * 8;
#pragma unroll
        for (int kb = 0; kb < 4; kb++) {
            float4 x = *(const float4*)(qp + kb * 32);
            float4 y = *(const float4*)(qp + kb * 32 + 4);
            qf[nq][kb] = (f16x8){
                (f16)(x.x * SCALE_LOG2E), (f16)(x.y * SCALE_LOG2E),
                (f16)(x.z * SCALE_LOG2E), (f16)(x.w * SCALE_LOG2E),
                (f16)(y.x * SCALE_LOG2E), (f16)(y.y * SCALE_LOG2E),
                (f16)(y.z * SCALE_LOG2E), (f16)(y.w * SCALE_LOG2E) };
        }
    }

    f32x4 zero4 = { 0.f, 0.f, 0.f, 0.f };
    f32x4 oacc[8][2];
#pragma unroll
    for (int mi = 0; mi < 8; mi++) { oacc[mi][0] = zero4; oacc[mi][1] = zero4; }
    float m_i[2] = { -1e30f, -1e30f };
    float l_i[2] = { 0.f, 0.f };

    const f16* kfb = kf + (size_t)(b * 8 + hk) * (S * D);
    const f16* vfb = vf + (size_t)(b * 8 + hk) * (S * D);

    int nt = qwb / 64 + 1;             // tiles needed (causal)

    for (int kt = 0; kt < nt; kt++) {
        f32x4 sacc[4][2];
#pragma unroll
        for (int mb = 0; mb < 4; mb++) { sacc[mb][0] = zero4; sacc[mb][1] = zero4; }
        __builtin_amdgcn_s_setprio(1);
#pragma unroll
        for (int mb = 0; mb < 4; mb++) {
            const f16* ka = kfb + (size_t)(((kt * 4 + mb) * 4) * 64 + lane) * 8;
#pragma unroll
            for (int kb = 0; kb < 4; kb++) {
                f16x8 af = *(const f16x8*)(ka + kb * 512);
                sacc[mb][0] = __builtin_amdgcn_mfma_f32_16x16x32_f16(af, qf[0][kb], sacc[mb][0], 0, 0, 0);
                sacc[mb][1] = __builtin_amdgcn_mfma_f32_16x16x32_f16(af, qf[1][kb], sacc[mb][1], 0, 0, 0);
            }
        }
        __builtin_amdgcn_s_setprio(0);

        // online softmax with defer-max (THR=8 in log2 domain)
        bool diag = (kt == nt - 1);
        f16x4 pf[4][2];
#pragma unroll
        for (int nq = 0; nq < 2; nq++) {
            float mt = -1e30f;
            if (diag) {
                int qg = qwb + nq * 16 + lq;
#pragma unroll
                for (int mb = 0; mb < 4; mb++)
#pragma unroll
                    for (int r4 = 0; r4 < 4; r4++) {
                        float vs = sacc[mb][nq][r4];
                        int key = kt * 64 + mb * 16 + quad * 4 + r4;
                        vs = (key <= qg) ? vs : -1e30f;
                        sacc[mb][nq][r4] = vs;
                        mt = fmaxf(mt, vs);
                    }
            } else {
#pragma unroll
                for (int mb = 0; mb < 4; mb++)
#pragma unroll
                    for (int r4 = 0; r4 < 4; r4++)
                        mt = fmaxf(mt, sacc[mb][nq][r4]);
            }
            mt = fmaxf(mt, __shfl_xor(mt, 16, 64));
            mt = fmaxf(mt, __shfl_xor(mt, 32, 64));
            float mnew = m_i[nq];
            if (!__all(mt <= mnew + 8.0f)) {   // wave-uniform: rescale rarely
                mnew = fmaxf(mnew, mt);
                float a = exp2f(m_i[nq] - mnew);
                m_i[nq] = mnew;
                l_i[nq] *= a;
#pragma unroll
                for (int mi = 0; mi < 8; mi++) oacc[mi][nq] = oacc[mi][nq] * a;
            }
            float ls = 0.f;
#pragma unroll
            for (int mb = 0; mb < 4; mb++) {
#pragma unroll
                for (int r4 = 0; r4 < 4; r4++) {
                    float e = exp2f(sacc[mb][nq][r4] - mnew);
                    sacc[mb][nq][r4] = e;
                    ls += e;
                }
                auto lo = __builtin_amdgcn_cvt_pkrtz(sacc[mb][nq][0], sacc[mb][nq][1]);
                auto hi = __builtin_amdgcn_cvt_pkrtz(sacc[mb][nq][2], sacc[mb][nq][3]);
                pf[mb][nq] = (f16x4){ (f16)lo[0], (f16)lo[1], (f16)hi[0], (f16)hi[1] };
            }
            ls += __shfl_xor(ls, 16, 64);
            ls += __shfl_xor(ls, 32, 64);
            l_i[nq] += ls;
        }

        // O^T += V^T . P^T
        __builtin_amdgcn_s_setprio(1);
#pragma unroll
        for (int mi = 0; mi < 8; mi++) {
            const f16* va = vfb + (size_t)(((kt * 8 + mi) * 2) * 64 + lane) * 8;
#pragma unroll
            for (int ks2 = 0; ks2 < 2; ks2++) {
                f16x8 vv = *(const f16x8*)(va + ks2 * 512);
                f16x4 v0 = { vv[0], vv[1], vv[2], vv[3] };
                f16x4 v1 = { vv[4], vv[5], vv[6], vv[7] };
                oacc[mi][0] = __builtin_amdgcn_mfma_f32_16x16x16f16(v0, pf[ks2 * 2 + 0][0], oacc[mi][0], 0, 0, 0);
                oacc[mi][0] = __builtin_amdgcn_mfma_f32_16x16x16f16(v1, pf[ks2 * 2 + 1][0], oacc[mi][0], 0, 0, 0);
                oacc[mi][1] = __builtin_amdgcn_mfma_f32_16x16x16f16(v0, pf[ks2 * 2 + 0][1], oacc[mi][1], 0, 0, 0);
                oacc[mi][1] = __builtin_amdgcn_mfma_f32_16x16x16f16(v1, pf[ks2 * 2 + 1][1], oacc[mi][1], 0, 0, 0);
            }
        }
        __builtin_amdgcn_s_setprio(0);
    }

    // epilogue
#pragma unroll
    for (int nq = 0; nq < 2; nq++) {
        float linv = 1.0f / l_i[nq];
        int qg = qwb + nq * 16 + lq;
        float* op = out + ((size_t)(b * S + qg) * HQ + hq) * D + quad * 4;
#pragma unroll
        for (int mi = 0; mi < 8; mi++) {
            float4 vv = { oacc[mi][nq][0] * linv, oacc[mi][nq][1] * linv,
                          oacc[mi][nq][2] * linv, oacc[mi][nq][3] * linv };
            *(float4*)(op + mi * 16) = vv;
        }
    }
}

extern "C" void kernel_launch(void* const* d_in, const int* in_sizes, int n_in,
                              void* d_out, int out_size, void* d_ws, size_t ws_size,
                              hipStream_t stream) {
    (void)in_sizes; (void)n_in; (void)out_size; (void)ws_size;
    const float* q = (const float*)d_in[0];
    const float* k = (const float*)d_in[1];
    const float* v = (const float*)d_in[2];
    // paged-cache scatter/gather round-trip is identity for the output -> skip
    float* out = (float*)d_out;

    f16* kf = (f16*)d_ws;                                  // 16.8 MB
    f16* vf = kf + (size_t)NB * HKV * S * D;               // 16.8 MB

    pack_kernel<<<1024, 256, 0, stream>>>(k, v, kf, vf);
    attn_kernel<<<NB * HQ * 8, 256, 0, stream>>>(q, kf, vf, out);
}

// Round 5
// 409.019 us; speedup vs baseline: 1.2025x; 1.1268x over previous
//
#include <hip/hip_runtime.h>

typedef _Float16 f16;
typedef __attribute__((ext_vector_type(8))) _Float16 f16x8;
typedef __attribute__((ext_vector_type(4))) _Float16 f16x4;
typedef __attribute__((ext_vector_type(4))) float f32x4;

constexpr int HQ = 32, HKV = 8, D = 128, NB = 8, S = 1024;
constexpr float SCALE_LOG2E = 0.08838834764831845f * 1.4426950408889634f;

// async global->LDS, 16B per lane: LDS dest = uniform base + lane*16
static __device__ __forceinline__ void gload16(const f16* g, f16* l) {
    __builtin_amdgcn_global_load_lds(
        (const __attribute__((address_space(1))) void*)g,
        (__attribute__((address_space(3))) void*)l, 16, 0, 0);
}

// ---- pack: K and V fp32 [t][h][d] -> fragment-major f16, via LDS transpose ----
// K chunk layout: c = [b][hk][tile(16)][mb(4)][kb(4)][lane(64)], elem j:
//   K[s = tile*64+mb*16+lq][d = kb*32+quad*8+j],  lane = quad*16+lq
// V chunk layout: c = [b][hk][tile(16)][mi(8)][ks2(2)][lane(64)], elem (o,j):
//   V[s = tile*64+ks2*32+o*16+quad*4+j][d = mi*16+lq]
__global__ __launch_bounds__(256) void pack_kernel(const float* __restrict__ k,
                                                   const float* __restrict__ v,
                                                   f16* __restrict__ kf,
                                                   f16* __restrict__ vf) {
    __shared__ __attribute__((aligned(16))) f16 tile[64][136];
    int blk = blockIdx.x;              // 1024 = b(8) hk(8) tile(16)
    int tl = blk & 15, hk = (blk >> 4) & 7, b = blk >> 7;
    int t = threadIdx.x;
    size_t cbase = ((size_t)(b * 8 + hk) * 16 + tl) * 1024;

    const float* kin = k + ((size_t)(b * S + tl * 64) * HKV + hk) * D;
#pragma unroll
    for (int i = 0; i < 8; i++) {
        int flat = t + 256 * i;
        int row = flat >> 5, c4 = flat & 31;
        float4 x = *(const float4*)(kin + (size_t)row * (HKV * D) + c4 * 4);
        *(f16x4*)&tile[row][c4 * 4] = (f16x4){ (f16)x.x,(f16)x.y,(f16)x.z,(f16)x.w };
    }
    __syncthreads();
#pragma unroll
    for (int i = 0; i < 4; i++) {
        int c_loc = t + 256 * i;
        int mb = c_loc >> 8, kb = (c_loc >> 6) & 3, lane = c_loc & 63;
        int quad = lane >> 4, lq = lane & 15;
        f16x8 o = *(const f16x8*)&tile[mb * 16 + lq][kb * 32 + quad * 8];
        *(f16x8*)(kf + (cbase + c_loc) * 8) = o;
    }
    __syncthreads();

    const float* vin = v + ((size_t)(b * S + tl * 64) * HKV + hk) * D;
#pragma unroll
    for (int i = 0; i < 8; i++) {
        int flat = t + 256 * i;
        int row = flat >> 5, c4 = flat & 31;
        float4 x = *(const float4*)(vin + (size_t)row * (HKV * D) + c4 * 4);
        *(f16x4*)&tile[row][c4 * 4] = (f16x4){ (f16)x.x,(f16)x.y,(f16)x.z,(f16)x.w };
    }
    __syncthreads();
#pragma unroll
    for (int i = 0; i < 4; i++) {
        int c_loc = t + 256 * i;
        int mi = c_loc >> 7, ks2 = (c_loc >> 6) & 1, lane = c_loc & 63;
        int quad = lane >> 4, lq = lane & 15;
        int d = mi * 16 + lq;
        f16 buf[8];
#pragma unroll
        for (int o = 0; o < 2; o++)
#pragma unroll
            for (int j = 0; j < 4; j++)
                buf[o * 4 + j] = tile[ks2 * 32 + o * 16 + quad * 4 + j][d];
        *(f16x8*)(vf + (cbase + c_loc) * 8) = *(const f16x8*)buf;
    }
}

// ---- attention: LDS-staged double-buffered 2-phase flash (T3-minimum) ----
// Per kt: all 4 waves cooperatively prefetch tile kt+1 (K 16KB + V 16KB,
// fragment-major-linear -> global_load_lds width 16, zero layout change)
// while computing tile kt from the other LDS buffer. One __syncthreads per
// iteration: its vmcnt(0) drain lands a full compute-phase after the STAGE
// issue. Loop bound ntmax is block-uniform; per-wave causal guard wraps
// compute only, so barriers never diverge.
__global__ __launch_bounds__(256, 2) void attn_kernel(
    const float* __restrict__ q, const f16* __restrict__ kf,
    const f16* __restrict__ vf, float* __restrict__ out) {

    __shared__ f16 ldsK[2][64 * 128];   // 2 x 16 KB
    __shared__ f16 ldsV[2][64 * 128];   // 2 x 16 KB

    int id = blockIdx.x;
    int xcd = id & 7;
    int slot = id >> 3;                // 0..255 within XCD
    int gl = slot >> 5;                // group-local index on this XCD
    int inner = slot & 31;             // 4 q-heads x 8 q-tiles
    int g = gl * 8 + xcd;              // (b,hk) group 0..63
    int b = g >> 3, hk = g & 7;
    int hq = (hk << 2) | (inner & 3);
    int qt = 7 - (((inner >> 2) + gl) & 7);

    int t = threadIdx.x;
    int w = t >> 6, lane = t & 63, quad = lane >> 4, lq = lane & 15;
    int qwb = qt * 128 + w * 32;       // wave's first query

    const f16* kfb = kf + (size_t)(b * 8 + hk) * (S * D);
    const f16* vfb = vf + (size_t)(b * 8 + hk) * (S * D);

    int nt = qwb / 64 + 1;             // this wave's causal tile count
    int ntmax = qt * 2 + 2;            // block-uniform loop bound

    // ---- prologue: stage tile 0 (issue before Q loads so it overlaps) ----
#pragma unroll
    for (int i = 0; i < 4; i++) {
        int sl = w * 4 + i;
        gload16(kfb + (size_t)(sl * 64 + lane) * 8, &ldsK[0][sl * 512]);
        gload16(vfb + (size_t)(sl * 64 + lane) * 8, &ldsV[0][sl * 512]);
    }

    // Q fragments, pre-scaled by SCALE_LOG2E
    f16x8 qf[2][4];
#pragma unroll
    for (int nq = 0; nq < 2; nq++) {
        int qg = qwb + nq * 16 + lq;
        const float* qp = q + ((size_t)(b * S + qg) * HQ + hq) * D + quad * 8;
#pragma unroll
        for (int kb = 0; kb < 4; kb++) {
            float4 x = *(const float4*)(qp + kb * 32);
            float4 y = *(const float4*)(qp + kb * 32 + 4);
            qf[nq][kb] = (f16x8){
                (f16)(x.x * SCALE_LOG2E), (f16)(x.y * SCALE_LOG2E),
                (f16)(x.z * SCALE_LOG2E), (f16)(x.w * SCALE_LOG2E),
                (f16)(y.x * SCALE_LOG2E), (f16)(y.y * SCALE_LOG2E),
                (f16)(y.z * SCALE_LOG2E), (f16)(y.w * SCALE_LOG2E) };
        }
    }

    f32x4 zero4 = { 0.f, 0.f, 0.f, 0.f };
    f32x4 oacc[8][2];
#pragma unroll
    for (int mi = 0; mi < 8; mi++) { oacc[mi][0] = zero4; oacc[mi][1] = zero4; }
    float m_i[2] = { -1e30f, -1e30f };
    float l_i[2] = { 0.f, 0.f };

    __syncthreads();                   // tile 0 staged (vmcnt(0) drain inside)

    int cur = 0;
    for (int kt = 0; kt < ntmax; kt++) {
        // ---- issue prefetch of tile kt+1 into the other buffer ----
        if (kt + 1 < ntmax) {
            const f16* kn = kfb + (size_t)(kt + 1) * (64 * 128);
            const f16* vn = vfb + (size_t)(kt + 1) * (64 * 128);
#pragma unroll
            for (int i = 0; i < 4; i++) {
                int sl = w * 4 + i;
                gload16(kn + (size_t)(sl * 64 + lane) * 8, &ldsK[cur ^ 1][sl * 512]);
                gload16(vn + (size_t)(sl * 64 + lane) * 8, &ldsV[cur ^ 1][sl * 512]);
            }
        }

        if (kt < nt) {                 // per-wave causal guard (no barriers inside)
            // S^T = K_tile . Q^T
            f32x4 sacc[4][2];
#pragma unroll
            for (int mb = 0; mb < 4; mb++) { sacc[mb][0] = zero4; sacc[mb][1] = zero4; }
            __builtin_amdgcn_s_setprio(1);
#pragma unroll
            for (int mb = 0; mb < 4; mb++) {
#pragma unroll
                for (int kb = 0; kb < 4; kb++) {
                    f16x8 af = *(const f16x8*)&ldsK[cur][((mb * 4 + kb) * 64 + lane) * 8];
                    sacc[mb][0] = __builtin_amdgcn_mfma_f32_16x16x32_f16(af, qf[0][kb], sacc[mb][0], 0, 0, 0);
                    sacc[mb][1] = __builtin_amdgcn_mfma_f32_16x16x32_f16(af, qf[1][kb], sacc[mb][1], 0, 0, 0);
                }
            }
            __builtin_amdgcn_s_setprio(0);

            // online softmax with defer-max (THR=8 in log2 domain)
            bool diag = (kt == nt - 1);
            f16x4 pf[4][2];
#pragma unroll
            for (int nq = 0; nq < 2; nq++) {
                float mt = -1e30f;
                if (diag) {
                    int qg = qwb + nq * 16 + lq;
#pragma unroll
                    for (int mb = 0; mb < 4; mb++)
#pragma unroll
                        for (int r4 = 0; r4 < 4; r4++) {
                            float vs = sacc[mb][nq][r4];
                            int key = kt * 64 + mb * 16 + quad * 4 + r4;
                            vs = (key <= qg) ? vs : -1e30f;
                            sacc[mb][nq][r4] = vs;
                            mt = fmaxf(mt, vs);
                        }
                } else {
#pragma unroll
                    for (int mb = 0; mb < 4; mb++)
#pragma unroll
                        for (int r4 = 0; r4 < 4; r4++)
                            mt = fmaxf(mt, sacc[mb][nq][r4]);
                }
                mt = fmaxf(mt, __shfl_xor(mt, 16, 64));
                mt = fmaxf(mt, __shfl_xor(mt, 32, 64));
                float mnew = m_i[nq];
                if (!__all(mt <= mnew + 8.0f)) {
                    mnew = fmaxf(mnew, mt);
                    float a = exp2f(m_i[nq] - mnew);
                    m_i[nq] = mnew;
                    l_i[nq] *= a;
#pragma unroll
                    for (int mi = 0; mi < 8; mi++) oacc[mi][nq] = oacc[mi][nq] * a;
                }
                float ls = 0.f;
#pragma unroll
                for (int mb = 0; mb < 4; mb++) {
#pragma unroll
                    for (int r4 = 0; r4 < 4; r4++) {
                        float e = exp2f(sacc[mb][nq][r4] - mnew);
                        sacc[mb][nq][r4] = e;
                        ls += e;
                    }
                    auto lo = __builtin_amdgcn_cvt_pkrtz(sacc[mb][nq][0], sacc[mb][nq][1]);
                    auto hi = __builtin_amdgcn_cvt_pkrtz(sacc[mb][nq][2], sacc[mb][nq][3]);
                    pf[mb][nq] = (f16x4){ (f16)lo[0], (f16)lo[1], (f16)hi[0], (f16)hi[1] };
                }
                ls += __shfl_xor(ls, 16, 64);
                ls += __shfl_xor(ls, 32, 64);
                l_i[nq] += ls;
            }

            // O^T += V^T . P^T
            __builtin_amdgcn_s_setprio(1);
#pragma unroll
            for (int mi = 0; mi < 8; mi++) {
#pragma unroll
                for (int ks2 = 0; ks2 < 2; ks2++) {
                    f16x8 vv = *(const f16x8*)&ldsV[cur][((mi * 2 + ks2) * 64 + lane) * 8];
                    f16x4 v0 = { vv[0], vv[1], vv[2], vv[3] };
                    f16x4 v1 = { vv[4], vv[5], vv[6], vv[7] };
                    oacc[mi][0] = __builtin_amdgcn_mfma_f32_16x16x16f16(v0, pf[ks2 * 2 + 0][0], oacc[mi][0], 0, 0, 0);
                    oacc[mi][0] = __builtin_amdgcn_mfma_f32_16x16x16f16(v1, pf[ks2 * 2 + 1][0], oacc[mi][0], 0, 0, 0);
                    oacc[mi][1] = __builtin_amdgcn_mfma_f32_16x16x16f16(v0, pf[ks2 * 2 + 0][1], oacc[mi][1], 0, 0, 0);
                    oacc[mi][1] = __builtin_amdgcn_mfma_f32_16x16x16f16(v1, pf[ks2 * 2 + 1][1], oacc[mi][1], 0, 0, 0);
                }
            }
            __builtin_amdgcn_s_setprio(0);
        }

        __syncthreads();               // vmcnt(0): tile kt+1 landed; buffers safe
        cur ^= 1;
    }

    // epilogue
#pragma unroll
    for (int nq = 0; nq < 2; nq++) {
        float linv = 1.0f / l_i[nq];
        int qg = qwb + nq * 16 + lq;
        float* op = out + ((size_t)(b * S + qg) * HQ + hq) * D + quad * 4;
#pragma unroll
        for (int mi = 0; mi < 8; mi++) {
            float4 vv = { oacc[mi][nq][0] * linv, oacc[mi][nq][1] * linv,
                          oacc[mi][nq][2] * linv, oacc[mi][nq][3] * linv };
            *(float4*)(op + mi * 16) = vv;
        }
    }
}

extern "C" void kernel_launch(void* const* d_in, const int* in_sizes, int n_in,
                              void* d_out, int out_size, void* d_ws, size_t ws_size,
                              hipStream_t stream) {
    (void)in_sizes; (void)n_in; (void)out_size; (void)ws_size;
    const float* q = (const float*)d_in[0];
    const float* k = (const float*)d_in[1];
    const float* v = (const float*)d_in[2];
    // paged-cache scatter/gather round-trip is identity for the output -> skip
    float* out = (float*)d_out;

    f16* kf = (f16*)d_ws;                                  // 16.8 MB
    f16* vf = kf + (size_t)NB * HKV * S * D;               // 16.8 MB

    pack_kernel<<<1024, 256, 0, stream>>>(k, v, kf, vf);
    attn_kernel<<<NB * HQ * 8, 256, 0, stream>>>(q, kf, vf, out);
}